// Round 1
// baseline (978.074 us; speedup 1.0000x reference)
//
#include <hip/hip_runtime.h>
#include <math.h>
#include <stdint.h>

typedef unsigned short u16;
typedef __attribute__((ext_vector_type(8))) short bf16x8;
typedef __attribute__((ext_vector_type(4))) float f32x4;

#define N_ 4096
#define D_ 1024
#define F_ 4096
#define M_ 2048
#define KG 307

#define BM 128
#define BN 128
#define BK 32

__device__ __forceinline__ u16 f2bf(float f) {
  unsigned int u = __float_as_uint(f);
  unsigned int r = u + 0x7fffu + ((u >> 16) & 1u);
  return (u16)(r >> 16);
}

__device__ __forceinline__ void gl_lds16(const u16* g, u16* l) {
  __builtin_amdgcn_global_load_lds(
      (__attribute__((address_space(1))) void*)(void*)g,
      (__attribute__((address_space(3))) void*)(void*)l,
      16, 0, 0);
}

enum { EP_F32 = 0, EP_BF16 = 1, EP_BF16T = 2, EP_SCALEMASK = 3, EP_BIAS = 4, EP_BIASGELU_BF16 = 5 };

// C[M,N] = A[M,K] @ B[N,K]^T   (A,B bf16 row-major, contiguous: lda=ldb=K)
template <int EPI>
__global__ __launch_bounds__(256) void gemm_nt(
    const u16* __restrict__ A, const u16* __restrict__ B, void* __restrict__ C,
    int M, int N, int K, const float* __restrict__ bias,
    const unsigned char* __restrict__ mask, float scale, int ldt) {
  __shared__ u16 As[BM * BK];
  __shared__ u16 Bs[BN * BK];
  const int tid = threadIdx.x;
  const int lane = tid & 63;
  const int wid = tid >> 6;
  const int wr = wid >> 1;
  const int wc = wid & 1;
  const int lr = lane & 15;
  const int lk = lane >> 4;
  const long bm = (long)blockIdx.x * BM;
  const long bn = (long)blockIdx.y * BN;

  f32x4 acc[4][4];
#pragma unroll
  for (int i = 0; i < 4; ++i)
#pragma unroll
    for (int j = 0; j < 4; ++j) acc[i][j] = f32x4{0.f, 0.f, 0.f, 0.f};

  for (int k0 = 0; k0 < K; k0 += BK) {
#pragma unroll
    for (int i = 0; i < 2; ++i) {
      int c = tid + i * 256;
      int r = c >> 2, cc = c & 3;  // 4 chunks of 16B per 32-elem row
      gl_lds16(A + (bm + r) * (long)K + k0 + cc * 8, As + c * 8);
    }
#pragma unroll
    for (int i = 0; i < 2; ++i) {
      int c = tid + i * 256;
      int r = c >> 2, cc = c & 3;
      gl_lds16(B + (bn + r) * (long)K + k0 + cc * 8, Bs + c * 8);
    }
    __syncthreads();
    bf16x8 av[4], bv[4];
#pragma unroll
    for (int mr = 0; mr < 4; ++mr)
      av[mr] = *(const bf16x8*)(As + (wr * 64 + mr * 16 + lr) * BK + lk * 8);
#pragma unroll
    for (int nr = 0; nr < 4; ++nr)
      bv[nr] = *(const bf16x8*)(Bs + (wc * 64 + nr * 16 + lr) * BK + lk * 8);
#pragma unroll
    for (int mr = 0; mr < 4; ++mr)
#pragma unroll
      for (int nr = 0; nr < 4; ++nr)
        acc[mr][nr] = __builtin_amdgcn_mfma_f32_16x16x32_bf16(av[mr], bv[nr], acc[mr][nr], 0, 0, 0);
    __syncthreads();
  }

#pragma unroll
  for (int mr = 0; mr < 4; ++mr) {
#pragma unroll
    for (int nr = 0; nr < 4; ++nr) {
#pragma unroll
      for (int j = 0; j < 4; ++j) {
        long row = bm + wr * 64 + mr * 16 + lk * 4 + j;  // C/D: col=lane&15, row=(lane>>4)*4+j
        long col = bn + wc * 64 + nr * 16 + lr;
        float v = acc[mr][nr][j];
        if constexpr (EPI == EP_F32) {
          ((float*)C)[row * N + col] = v;
        } else if constexpr (EPI == EP_BF16) {
          ((u16*)C)[row * N + col] = f2bf(v);
        } else if constexpr (EPI == EP_BF16T) {
          ((u16*)C)[col * (long)ldt + row] = f2bf(v);
        } else if constexpr (EPI == EP_SCALEMASK) {
          v *= scale;
          if (mask[row * N + col]) v = -1e9f;
          ((float*)C)[row * N + col] = v;
        } else if constexpr (EPI == EP_BIAS) {
          ((float*)C)[row * N + col] = v + bias[col];
        } else if constexpr (EPI == EP_BIASGELU_BF16) {
          float t = v + bias[col];
          float gl = 0.5f * t * (1.0f + erff(t * 0.70710678118654752f));
          ((u16*)C)[row * N + col] = f2bf(gl);
        }
      }
    }
  }
}

// out[c*R + r] = bf16(in[r*C + c])
__global__ __launch_bounds__(256) void tcvt(const float* __restrict__ in,
                                            u16* __restrict__ out, int R, int C) {
  __shared__ float tile[32][33];
  int bx = blockIdx.x * 32;  // col base
  int by = blockIdx.y * 32;  // row base
  int tx = threadIdx.x & 31;
  int ty = threadIdx.x >> 5;  // 0..7
#pragma unroll
  for (int i = 0; i < 32; i += 8)
    tile[ty + i][tx] = in[(long)(by + ty + i) * C + bx + tx];
  __syncthreads();
#pragma unroll
  for (int i = 0; i < 32; i += 8)
    out[(long)(bx + ty + i) * R + by + tx] = f2bf(tile[tx][ty + i]);
}

__global__ void copy_usex(const float* __restrict__ x, float* __restrict__ xf,
                          u16* __restrict__ xb, long n) {
  long i = (long)blockIdx.x * blockDim.x + threadIdx.x;
  if (i < n) {
    float v = x[i];
    xf[i] = v;
    xb[i] = f2bf(v);
  }
}

__global__ void mask_zero(const float* __restrict__ x, const int* __restrict__ mask_nodes,
                          const int* __restrict__ gene_idx, float* __restrict__ xf,
                          u16* __restrict__ xb, float* __restrict__ x_init) {
  int m = blockIdx.x;
  int k = threadIdx.x;
  if (k >= KG) return;
  int row = mask_nodes[m];
  int col = gene_idx[m * KG + k];
  x_init[m * KG + k] = x[(long)row * D_ + col];
  xf[(long)row * D_ + col] = 0.f;
  xb[(long)row * D_ + col] = 0;
}

// of/ob = LayerNorm(y_row + r_row) * g + b   (one block per row, D_=1024)
__global__ __launch_bounds__(256) void add_ln(const float* __restrict__ y,
                                              const float* __restrict__ r,
                                              const float* __restrict__ g,
                                              const float* __restrict__ b,
                                              float* __restrict__ of, u16* __restrict__ ob) {
  int row = blockIdx.x;
  const float* yr = y + (long)row * D_;
  const float* rr = r + (long)row * D_;
  float v[4];
  float s = 0.f, ss = 0.f;
#pragma unroll
  for (int i = 0; i < 4; ++i) {
    int idx = threadIdx.x + i * 256;
    float t = yr[idx] + rr[idx];
    v[i] = t;
    s += t;
    ss += t * t;
  }
#pragma unroll
  for (int o = 32; o > 0; o >>= 1) {
    s += __shfl_down(s, o, 64);
    ss += __shfl_down(ss, o, 64);
  }
  __shared__ float red[8];
  int wid = threadIdx.x >> 6, lane = threadIdx.x & 63;
  if (lane == 0) {
    red[wid] = s;
    red[4 + wid] = ss;
  }
  __syncthreads();
  if (threadIdx.x == 0) {
    red[0] = red[0] + red[1] + red[2] + red[3];
    red[4] = red[4] + red[5] + red[6] + red[7];
  }
  __syncthreads();
  float mu = red[0] * (1.f / D_);
  float var = red[4] * (1.f / D_) - mu * mu;
  float rs = rsqrtf(var + 1e-5f);
#pragma unroll
  for (int i = 0; i < 4; ++i) {
    int idx = threadIdx.x + i * 256;
    float o = (v[i] - mu) * rs * g[idx] + b[idx];
    of[(long)row * D_ + idx] = o;
    ob[(long)row * D_ + idx] = f2bf(o);
  }
}

// row softmax over N_=4096; writes bf16 (and optionally fp32, may alias input)
template <bool WF32>
__global__ __launch_bounds__(256) void softmax_row(const float* __restrict__ sin,
                                                   float* __restrict__ a32,
                                                   u16* __restrict__ a16) {
  int row = blockIdx.x;
  const float* sr = sin + (long)row * N_;
  float v[16];
  float mx = -3.0e38f;
#pragma unroll
  for (int i = 0; i < 16; ++i) {
    v[i] = sr[threadIdx.x + i * 256];
    mx = fmaxf(mx, v[i]);
  }
#pragma unroll
  for (int o = 32; o > 0; o >>= 1) mx = fmaxf(mx, __shfl_down(mx, o, 64));
  __shared__ float red[8];
  int wid = threadIdx.x >> 6, lane = threadIdx.x & 63;
  if (lane == 0) red[wid] = mx;
  __syncthreads();
  if (threadIdx.x == 0) red[0] = fmaxf(fmaxf(red[0], red[1]), fmaxf(red[2], red[3]));
  __syncthreads();
  mx = red[0];
  float sum = 0.f;
#pragma unroll
  for (int i = 0; i < 16; ++i) {
    v[i] = __expf(v[i] - mx);
    sum += v[i];
  }
#pragma unroll
  for (int o = 32; o > 0; o >>= 1) sum += __shfl_down(sum, o, 64);
  if (lane == 0) red[4 + wid] = sum;
  __syncthreads();
  if (threadIdx.x == 0) red[4] = red[4] + red[5] + red[6] + red[7];
  __syncthreads();
  float inv = 1.f / red[4];
#pragma unroll
  for (int i = 0; i < 16; ++i) {
    float p = v[i] * inv;
    long off = (long)row * N_ + threadIdx.x + i * 256;
    if constexpr (WF32) a32[off] = p;
    a16[off] = f2bf(p);
  }
}

__global__ void gather_rows(const u16* __restrict__ src, const int* __restrict__ mask_nodes,
                            u16* __restrict__ dst) {
  int m = blockIdx.x;
  int row = mask_nodes[m];
  for (int i = threadIdx.x; i < D_; i += 256)
    dst[(long)m * D_ + i] = src[(long)row * D_ + i];
}

__global__ void gather_recon(const float* __restrict__ h, const int* __restrict__ gene_idx,
                             float* __restrict__ xr) {
  int m = blockIdx.x;
  int k = threadIdx.x;
  if (k >= KG) return;
  xr[m * KG + k] = h[(long)m * D_ + gene_idx[m * KG + k]];
}

extern "C" void kernel_launch(void* const* d_in, const int* in_sizes, int n_in,
                              void* d_out, int out_size, void* d_ws, size_t ws_size,
                              hipStream_t stream) {
  const float* x = (const float*)d_in[0];
  const unsigned char* real_mask = (const unsigned char*)d_in[1];
  const int* mask_nodes = (const int*)d_in[3];
  const int* gene_idx = (const int*)d_in[4];
  const float* wq1 = (const float*)d_in[5];
  const float* wk1 = (const float*)d_in[6];
  const float* wv1 = (const float*)d_in[7];
  const float* g1 = (const float*)d_in[8];
  const float* be1 = (const float*)d_in[9];
  const float* fw1 = (const float*)d_in[10];
  const float* fb1 = (const float*)d_in[11];
  const float* fw2 = (const float*)d_in[12];
  const float* fb2 = (const float*)d_in[13];
  const float* g2 = (const float*)d_in[14];
  const float* be2 = (const float*)d_in[15];
  const float* wq2 = (const float*)d_in[16];
  const float* wk2 = (const float*)d_in[17];
  const float* wv2 = (const float*)d_in[18];
  const float* g3 = (const float*)d_in[19];
  const float* be3 = (const float*)d_in[20];
  const float* hw1 = (const float*)d_in[21];
  const float* hb1 = (const float*)d_in[22];
  const float* hw2 = (const float*)d_in[23];
  const float* hb2 = (const float*)d_in[24];
  const float* g4 = (const float*)d_in[25];
  const float* be4 = (const float*)d_in[26];
  const float* head_w = (const float*)d_in[27];
  const float* head_b = (const float*)d_in[28];

  float* out_xinit = (float*)d_out;
  float* out_xrecon = out_xinit + (long)M_ * KG;
  float* out_enc = out_xrecon + (long)M_ * KG;
  float* out_recon = out_enc + (long)N_ * N_;

  char* w = (char*)d_ws;
  size_t off = 0;
  auto alloc = [&](size_t bytes) {
    void* p = w + off;
    off += (bytes + 255) & ~(size_t)255;
    return p;
  };
  float* useXf = (float*)alloc((size_t)N_ * D_ * 4);
  u16* useXb = (u16*)alloc((size_t)N_ * D_ * 2);
  u16* wslot = (u16*)alloc((size_t)D_ * F_ * 2);
  u16* qb = (u16*)alloc((size_t)N_ * D_ * 2);
  u16* kb = (u16*)alloc((size_t)N_ * D_ * 2);
  u16* vT = (u16*)alloc((size_t)N_ * D_ * 2);
  float* sbuf = (float*)alloc((size_t)N_ * N_ * 4);
  u16* aB = (u16*)alloc((size_t)N_ * N_ * 2);
  float* gout = (float*)alloc((size_t)N_ * D_ * 4);
  float* actA = (float*)alloc((size_t)N_ * D_ * 4);
  float* actB = (float*)alloc((size_t)N_ * D_ * 4);
  u16* actB16 = (u16*)alloc((size_t)N_ * D_ * 2);
  u16* tbuf = (u16*)sbuf;  // FFN intermediate (bf16, 32MB) shares the s2 buffer
  u16* AgB = qb;           // gathered masked rows (bf16) reuse q buffer

  const float scale = 1.0f / 32.0f;  // 1/sqrt(D_)
  dim3 blk(256);

  // ---- use_x = x with K genes zeroed in each masked row; x_init gather
  long nd = (long)N_ * D_;
  copy_usex<<<dim3((unsigned)((nd + 255) / 256)), blk, 0, stream>>>(x, useXf, useXb, nd);
  mask_zero<<<dim3(M_), 320, 0, stream>>>(x, mask_nodes, gene_idx, useXf, useXb, out_xinit);

#define TCVT(src, R, C) tcvt<<<dim3((C) / 32, (R) / 32), blk, 0, stream>>>(src, wslot, R, C)

  // ---- block 1: attention
  TCVT(wq1, D_, D_);
  gemm_nt<EP_BF16><<<dim3(N_ / 128, D_ / 128), blk, 0, stream>>>(useXb, wslot, qb, N_, D_, D_, nullptr, nullptr, 0.f, 0);
  TCVT(wk1, D_, D_);
  gemm_nt<EP_BF16><<<dim3(N_ / 128, D_ / 128), blk, 0, stream>>>(useXb, wslot, kb, N_, D_, D_, nullptr, nullptr, 0.f, 0);
  TCVT(wv1, D_, D_);
  gemm_nt<EP_BF16T><<<dim3(N_ / 128, D_ / 128), blk, 0, stream>>>(useXb, wslot, vT, N_, D_, D_, nullptr, nullptr, 0.f, N_);
  gemm_nt<EP_SCALEMASK><<<dim3(N_ / 128, N_ / 128), blk, 0, stream>>>(qb, kb, out_enc, N_, N_, D_, nullptr, real_mask, scale, 0);
  softmax_row<true><<<dim3(N_), blk, 0, stream>>>(out_enc, out_enc, aB);
  gemm_nt<EP_F32><<<dim3(N_ / 128, D_ / 128), blk, 0, stream>>>(aB, vT, gout, N_, D_, N_, nullptr, nullptr, 0.f, 0);
  add_ln<<<dim3(N_), blk, 0, stream>>>(gout, useXf, g1, be1, actA, actB16);
  // ---- block 1: FFN
  TCVT(fw1, D_, F_);
  gemm_nt<EP_BIASGELU_BF16><<<dim3(N_ / 128, F_ / 128), blk, 0, stream>>>(actB16, wslot, tbuf, N_, F_, D_, fb1, nullptr, 0.f, 0);
  TCVT(fw2, F_, D_);
  gemm_nt<EP_BIAS><<<dim3(N_ / 128, D_ / 128), blk, 0, stream>>>(tbuf, wslot, gout, N_, D_, F_, fb2, nullptr, 0.f, 0);
  add_ln<<<dim3(N_), blk, 0, stream>>>(gout, actA, g2, be2, actB, actB16);

  // ---- block 2: attention
  TCVT(wq2, D_, D_);
  gemm_nt<EP_BF16><<<dim3(N_ / 128, D_ / 128), blk, 0, stream>>>(actB16, wslot, qb, N_, D_, D_, nullptr, nullptr, 0.f, 0);
  TCVT(wk2, D_, D_);
  gemm_nt<EP_BF16><<<dim3(N_ / 128, D_ / 128), blk, 0, stream>>>(actB16, wslot, kb, N_, D_, D_, nullptr, nullptr, 0.f, 0);
  TCVT(wv2, D_, D_);
  gemm_nt<EP_BF16T><<<dim3(N_ / 128, D_ / 128), blk, 0, stream>>>(actB16, wslot, vT, N_, D_, D_, nullptr, nullptr, 0.f, N_);
  gemm_nt<EP_SCALEMASK><<<dim3(N_ / 128, N_ / 128), blk, 0, stream>>>(qb, kb, sbuf, N_, N_, D_, nullptr, real_mask, scale, 0);
  softmax_row<false><<<dim3(N_), blk, 0, stream>>>(sbuf, nullptr, aB);
  gemm_nt<EP_F32><<<dim3(N_ / 128, D_ / 128), blk, 0, stream>>>(aB, vT, gout, N_, D_, N_, nullptr, nullptr, 0.f, 0);
  add_ln<<<dim3(N_), blk, 0, stream>>>(gout, actB, g3, be3, actA, actB16);
  // ---- block 2: FFN
  TCVT(hw1, D_, F_);
  gemm_nt<EP_BIASGELU_BF16><<<dim3(N_ / 128, F_ / 128), blk, 0, stream>>>(actB16, wslot, tbuf, N_, F_, D_, hb1, nullptr, 0.f, 0);
  TCVT(hw2, F_, D_);
  gemm_nt<EP_BIAS><<<dim3(N_ / 128, D_ / 128), blk, 0, stream>>>(tbuf, wslot, gout, N_, D_, F_, hb2, nullptr, 0.f, 0);
  add_ln<<<dim3(N_), blk, 0, stream>>>(gout, actA, g4, be4, out_recon, actB16);

  // ---- head (only masked rows) + gathers
  gather_rows<<<dim3(M_), blk, 0, stream>>>(actB16, mask_nodes, AgB);
  TCVT(head_w, D_, D_);
  gemm_nt<EP_BIAS><<<dim3(M_ / 128, D_ / 128), blk, 0, stream>>>(AgB, wslot, gout, M_, D_, D_, head_b, nullptr, 0.f, 0);
  gather_recon<<<dim3(M_), 320, 0, stream>>>(gout, gene_idx, out_xrecon);
#undef TCVT
}

// Round 2
// 747.895 us; speedup vs baseline: 1.3078x; 1.3078x over previous
//
#include <hip/hip_runtime.h>
#include <math.h>
#include <stdint.h>

typedef unsigned short u16;
typedef __attribute__((ext_vector_type(8))) short bf16x8;
typedef __attribute__((ext_vector_type(4))) float f32x4;

#define N_ 4096
#define D_ 1024
#define F_ 4096
#define M_ 2048
#define KG 307

#define BM 128
#define BN 128
#define BK 32

__device__ __forceinline__ u16 f2bf(float f) {
  unsigned int u = __float_as_uint(f);
  unsigned int r = u + 0x7fffu + ((u >> 16) & 1u);
  return (u16)(r >> 16);
}

__device__ __forceinline__ void gl_lds16(const u16* g, u16* l) {
  __builtin_amdgcn_global_load_lds(
      (__attribute__((address_space(1))) void*)(void*)g,
      (__attribute__((address_space(3))) void*)(void*)l,
      16, 0, 0);
}

enum { EP_F32S = 0, EP_QKV = 1, EP_SCALEMASK = 2, EP_BIASZ = 3, EP_BIASGELU_BF16 = 4 };

// C[M,N] = A[M,K] @ B[N,K]^T, bf16 in / fp32 acc. 2-phase double-buffered LDS.
// blockIdx.z = K-split slice (each does Ksp of K, offset z*Ksp).
template <int EPI>
__global__ __launch_bounds__(256) void gemm_nt(
    const u16* __restrict__ A, const u16* __restrict__ B,
    void* __restrict__ C, void* __restrict__ C2,
    int Ndim, int Ksp, int lda, int ldb,
    const float* __restrict__ bias, const unsigned char* __restrict__ mask,
    float scale) {
  __shared__ u16 As[2][BM * BK];
  __shared__ u16 Bs[2][BN * BK];
  const int tid = threadIdx.x;
  const int lane = tid & 63;
  const int wid = tid >> 6;
  const int wr = wid >> 1;
  const int wc = wid & 1;
  const int lr = lane & 15;
  const int lk = lane >> 4;
  const long bm = (long)blockIdx.x * BM;
  const long bn = (long)blockIdx.y * BN;
  const long koff = (long)blockIdx.z * Ksp;

  f32x4 acc[4][4];
#pragma unroll
  for (int i = 0; i < 4; ++i)
#pragma unroll
    for (int j = 0; j < 4; ++j) acc[i][j] = f32x4{0.f, 0.f, 0.f, 0.f};

  auto stage = [&](int buf, long k0) {
#pragma unroll
    for (int i = 0; i < 2; ++i) {
      int c = tid + i * 256;
      gl_lds16(A + (bm + (c >> 2)) * (long)lda + k0 + (c & 3) * 8, As[buf] + c * 8);
    }
#pragma unroll
    for (int i = 0; i < 2; ++i) {
      int c = tid + i * 256;
      gl_lds16(B + (bn + (c >> 2)) * (long)ldb + k0 + (c & 3) * 8, Bs[buf] + c * 8);
    }
  };

  stage(0, koff);
  __syncthreads();
  const int nt = Ksp / BK;
  int cur = 0;
  for (int t = 0; t < nt; ++t) {
    if (t + 1 < nt) stage(cur ^ 1, koff + (long)(t + 1) * BK);  // prefetch next tile
    bf16x8 av[4], bv[4];
#pragma unroll
    for (int mr = 0; mr < 4; ++mr)
      av[mr] = *(const bf16x8*)(As[cur] + (wr * 64 + mr * 16 + lr) * BK + lk * 8);
#pragma unroll
    for (int nr = 0; nr < 4; ++nr)
      bv[nr] = *(const bf16x8*)(Bs[cur] + (wc * 64 + nr * 16 + lr) * BK + lk * 8);
#pragma unroll
    for (int mr = 0; mr < 4; ++mr)
#pragma unroll
      for (int nr = 0; nr < 4; ++nr)
        acc[mr][nr] = __builtin_amdgcn_mfma_f32_16x16x32_bf16(av[mr], bv[nr], acc[mr][nr], 0, 0, 0);
    __syncthreads();  // drains vmcnt(0): prefetched tile is ready; buf[cur] free
    cur ^= 1;
  }

  const bool z0 = (blockIdx.z == 0);
#pragma unroll
  for (int mr = 0; mr < 4; ++mr) {
#pragma unroll
    for (int nr = 0; nr < 4; ++nr) {
#pragma unroll
      for (int j = 0; j < 4; ++j) {
        long row = bm + wr * 64 + mr * 16 + lk * 4 + j;  // C/D: col=lane&15, row=(lane>>4)*4+j
        long col = bn + wc * 64 + nr * 16 + lr;
        float v = acc[mr][nr][j];
        if constexpr (EPI == EP_F32S) {
          ((float*)(z0 ? C : C2))[row * Ndim + col] = v;
        } else if constexpr (EPI == EP_QKV) {
          if (col < 2048)
            ((u16*)C)[row * 2048 + col] = f2bf(v);
          else
            ((u16*)C2)[(col - 2048) * (long)N_ + row] = f2bf(v);
        } else if constexpr (EPI == EP_SCALEMASK) {
          v *= scale;
          if (mask[row * Ndim + col]) v = -1e9f;
          ((float*)C)[row * Ndim + col] = v;
        } else if constexpr (EPI == EP_BIASZ) {
          ((float*)(z0 ? C : C2))[row * Ndim + col] = v + (z0 ? bias[col] : 0.f);
        } else if constexpr (EPI == EP_BIASGELU_BF16) {
          float t = v + bias[col];
          float gl = 0.5f * t * (1.0f + erff(t * 0.70710678118654752f));
          ((u16*)C)[row * Ndim + col] = f2bf(gl);
        }
      }
    }
  }
}

// out[c*R + r] = bf16(in[r*C + c])
__global__ __launch_bounds__(256) void tcvt(const float* __restrict__ in,
                                            u16* __restrict__ out, int R, int C) {
  __shared__ float tile[32][33];
  int bx = blockIdx.x * 32;
  int by = blockIdx.y * 32;
  int tx = threadIdx.x & 31;
  int ty = threadIdx.x >> 5;
#pragma unroll
  for (int i = 0; i < 32; i += 8)
    tile[ty + i][tx] = in[(long)(by + ty + i) * C + bx + tx];
  __syncthreads();
#pragma unroll
  for (int i = 0; i < 32; i += 8)
    out[(long)(bx + ty + i) * R + by + tx] = f2bf(tile[tx][ty + i]);
}

__global__ void copy_usex(const float* __restrict__ x, float* __restrict__ xf,
                          u16* __restrict__ xb, long n) {
  long i = (long)blockIdx.x * blockDim.x + threadIdx.x;
  if (i < n) {
    float v = x[i];
    xf[i] = v;
    xb[i] = f2bf(v);
  }
}

__global__ void mask_zero(const float* __restrict__ x, const int* __restrict__ mask_nodes,
                          const int* __restrict__ gene_idx, float* __restrict__ xf,
                          u16* __restrict__ xb, float* __restrict__ x_init) {
  int m = blockIdx.x;
  int k = threadIdx.x;
  if (k >= KG) return;
  int row = mask_nodes[m];
  int col = gene_idx[m * KG + k];
  x_init[m * KG + k] = x[(long)row * D_ + col];
  xf[(long)row * D_ + col] = 0.f;
  xb[(long)row * D_ + col] = 0;
}

// of/ob = LayerNorm(y + [y2] + r) * g + b  (one block per row, D_=1024)
template <bool TWO>
__global__ __launch_bounds__(256) void add_ln(const float* __restrict__ y,
                                              const float* __restrict__ y2,
                                              const float* __restrict__ r,
                                              const float* __restrict__ g,
                                              const float* __restrict__ b,
                                              float* __restrict__ of, u16* __restrict__ ob) {
  int row = blockIdx.x;
  const float* yr = y + (long)row * D_;
  const float* y2r = TWO ? y2 + (long)row * D_ : nullptr;
  const float* rr = r + (long)row * D_;
  float v[4];
  float s = 0.f, ss = 0.f;
#pragma unroll
  for (int i = 0; i < 4; ++i) {
    int idx = threadIdx.x + i * 256;
    float t = yr[idx] + rr[idx];
    if constexpr (TWO) t += y2r[idx];
    v[i] = t;
    s += t;
    ss += t * t;
  }
#pragma unroll
  for (int o = 32; o > 0; o >>= 1) {
    s += __shfl_down(s, o, 64);
    ss += __shfl_down(ss, o, 64);
  }
  __shared__ float red[8];
  int wid = threadIdx.x >> 6, lane = threadIdx.x & 63;
  if (lane == 0) {
    red[wid] = s;
    red[4 + wid] = ss;
  }
  __syncthreads();
  if (threadIdx.x == 0) {
    red[0] = red[0] + red[1] + red[2] + red[3];
    red[4] = red[4] + red[5] + red[6] + red[7];
  }
  __syncthreads();
  float mu = red[0] * (1.f / D_);
  float var = red[4] * (1.f / D_) - mu * mu;
  float rs = rsqrtf(var + 1e-5f);
#pragma unroll
  for (int i = 0; i < 4; ++i) {
    int idx = threadIdx.x + i * 256;
    float o = (v[i] - mu) * rs * g[idx] + b[idx];
    of[(long)row * D_ + idx] = o;
    ob[(long)row * D_ + idx] = f2bf(o);
  }
}

// row softmax over N_=4096; writes bf16 (and optionally fp32 in-place)
template <bool WF32>
__global__ __launch_bounds__(256) void softmax_row(const float* __restrict__ sin,
                                                   float* __restrict__ a32,
                                                   u16* __restrict__ a16) {
  int row = blockIdx.x;
  const float* sr = sin + (long)row * N_;
  float v[16];
  float mx = -3.0e38f;
#pragma unroll
  for (int i = 0; i < 16; ++i) {
    v[i] = sr[threadIdx.x + i * 256];
    mx = fmaxf(mx, v[i]);
  }
#pragma unroll
  for (int o = 32; o > 0; o >>= 1) mx = fmaxf(mx, __shfl_down(mx, o, 64));
  __shared__ float red[8];
  int wid = threadIdx.x >> 6, lane = threadIdx.x & 63;
  if (lane == 0) red[wid] = mx;
  __syncthreads();
  if (threadIdx.x == 0) red[0] = fmaxf(fmaxf(red[0], red[1]), fmaxf(red[2], red[3]));
  __syncthreads();
  mx = red[0];
  float sum = 0.f;
#pragma unroll
  for (int i = 0; i < 16; ++i) {
    v[i] = __expf(v[i] - mx);
    sum += v[i];
  }
#pragma unroll
  for (int o = 32; o > 0; o >>= 1) sum += __shfl_down(sum, o, 64);
  if (lane == 0) red[4 + wid] = sum;
  __syncthreads();
  if (threadIdx.x == 0) red[4] = red[4] + red[5] + red[6] + red[7];
  __syncthreads();
  float inv = 1.f / red[4];
#pragma unroll
  for (int i = 0; i < 16; ++i) {
    float p = v[i] * inv;
    long off = (long)row * N_ + threadIdx.x + i * 256;
    if constexpr (WF32) a32[off] = p;
    a16[off] = f2bf(p);
  }
}

__global__ void gather_rows(const u16* __restrict__ src, const int* __restrict__ mask_nodes,
                            u16* __restrict__ dst) {
  int m = blockIdx.x;
  int row = mask_nodes[m];
  for (int i = threadIdx.x; i < D_; i += 256)
    dst[(long)m * D_ + i] = src[(long)row * D_ + i];
}

__global__ void gather_recon(const float* __restrict__ h, const int* __restrict__ gene_idx,
                             float* __restrict__ xr) {
  int m = blockIdx.x;
  int k = threadIdx.x;
  if (k >= KG) return;
  xr[m * KG + k] = h[(long)m * D_ + gene_idx[m * KG + k]];
}

extern "C" void kernel_launch(void* const* d_in, const int* in_sizes, int n_in,
                              void* d_out, int out_size, void* d_ws, size_t ws_size,
                              hipStream_t stream) {
  const float* x = (const float*)d_in[0];
  const unsigned char* real_mask = (const unsigned char*)d_in[1];
  const int* mask_nodes = (const int*)d_in[3];
  const int* gene_idx = (const int*)d_in[4];
  const float* wq1 = (const float*)d_in[5];
  const float* wk1 = (const float*)d_in[6];
  const float* wv1 = (const float*)d_in[7];
  const float* g1 = (const float*)d_in[8];
  const float* be1 = (const float*)d_in[9];
  const float* fw1 = (const float*)d_in[10];
  const float* fb1 = (const float*)d_in[11];
  const float* fw2 = (const float*)d_in[12];
  const float* fb2 = (const float*)d_in[13];
  const float* g2 = (const float*)d_in[14];
  const float* be2 = (const float*)d_in[15];
  const float* wq2 = (const float*)d_in[16];
  const float* wk2 = (const float*)d_in[17];
  const float* wv2 = (const float*)d_in[18];
  const float* g3 = (const float*)d_in[19];
  const float* be3 = (const float*)d_in[20];
  const float* hw1 = (const float*)d_in[21];
  const float* hb1 = (const float*)d_in[22];
  const float* hw2 = (const float*)d_in[23];
  const float* hb2 = (const float*)d_in[24];
  const float* g4 = (const float*)d_in[25];
  const float* be4 = (const float*)d_in[26];
  const float* head_w = (const float*)d_in[27];
  const float* head_b = (const float*)d_in[28];

  float* out_xinit = (float*)d_out;
  float* out_xrecon = out_xinit + (long)M_ * KG;
  float* out_enc = out_xrecon + (long)M_ * KG;
  float* out_recon = out_enc + (long)N_ * N_;

  char* w = (char*)d_ws;
  size_t off = 0;
  auto alloc = [&](size_t bytes) {
    void* p = w + off;
    off += (bytes + 255) & ~(size_t)255;
    return p;
  };
  float* useXf = (float*)alloc((size_t)N_ * D_ * 4);
  u16* useXb = (u16*)alloc((size_t)N_ * D_ * 2);
  u16* wslot = (u16*)alloc((size_t)D_ * F_ * 2);   // also holds fused qkv^T (6 MB)
  u16* qkb = (u16*)alloc((size_t)N_ * 2048 * 2);   // q|k  [4096][2048]
  u16* vT = (u16*)alloc((size_t)D_ * N_ * 2);      // v^T  [1024][4096]
  float* sbuf = (float*)alloc((size_t)N_ * N_ * 4);
  u16* aB = (u16*)alloc((size_t)N_ * N_ * 2);
  float* gout = (float*)alloc((size_t)N_ * D_ * 4);
  float* goutB = (float*)alloc((size_t)N_ * D_ * 4);
  float* actA = (float*)alloc((size_t)N_ * D_ * 4);
  float* actB = (float*)alloc((size_t)N_ * D_ * 4);
  u16* actB16 = (u16*)alloc((size_t)N_ * D_ * 2);
  u16* tbuf = (u16*)sbuf;  // FFN intermediate (bf16) aliases score buffer
  u16* AgB = qkb;          // gathered masked rows reuse q|k buffer

  const float scale = 1.0f / 32.0f;  // 1/sqrt(D_)
  dim3 blk(256);
  long nd = (long)N_ * D_;

  copy_usex<<<dim3((unsigned)((nd + 255) / 256)), blk, 0, stream>>>(x, useXf, useXb, nd);
  mask_zero<<<dim3(M_), 320, 0, stream>>>(x, mask_nodes, gene_idx, useXf, useXb, out_xinit);

#define TCVT(src, R, C, dst) tcvt<<<dim3((C) / 32, (R) / 32), blk, 0, stream>>>(src, dst, R, C)

  // ================= block 1 =================
  TCVT(wq1, D_, D_, wslot);
  TCVT(wk1, D_, D_, wslot + 1024 * 1024);
  TCVT(wv1, D_, D_, wslot + 2048 * 1024);
  gemm_nt<EP_QKV><<<dim3(32, 24, 1), blk, 0, stream>>>(useXb, wslot, qkb, vT, 3072, 1024, 1024, 1024, nullptr, nullptr, 0.f);
  gemm_nt<EP_SCALEMASK><<<dim3(32, 32, 1), blk, 0, stream>>>(qkb, qkb + 1024, out_enc, nullptr, N_, 1024, 2048, 2048, nullptr, real_mask, scale);
  softmax_row<true><<<dim3(N_), blk, 0, stream>>>(out_enc, out_enc, aB);
  gemm_nt<EP_F32S><<<dim3(32, 8, 2), blk, 0, stream>>>(aB, vT, gout, goutB, D_, 2048, 4096, 4096, nullptr, nullptr, 0.f);
  add_ln<true><<<dim3(N_), blk, 0, stream>>>(gout, goutB, useXf, g1, be1, actA, actB16);
  TCVT(fw1, D_, F_, wslot);
  gemm_nt<EP_BIASGELU_BF16><<<dim3(32, 32, 1), blk, 0, stream>>>(actB16, wslot, tbuf, nullptr, F_, 1024, 1024, 1024, fb1, nullptr, 0.f);
  TCVT(fw2, F_, D_, wslot);
  gemm_nt<EP_BIASZ><<<dim3(32, 8, 2), blk, 0, stream>>>(tbuf, wslot, gout, goutB, D_, 2048, 4096, 4096, fb2, nullptr, 0.f);
  add_ln<true><<<dim3(N_), blk, 0, stream>>>(gout, goutB, actA, g2, be2, actB, actB16);

  // ================= block 2 =================
  TCVT(wq2, D_, D_, wslot);
  TCVT(wk2, D_, D_, wslot + 1024 * 1024);
  TCVT(wv2, D_, D_, wslot + 2048 * 1024);
  gemm_nt<EP_QKV><<<dim3(32, 24, 1), blk, 0, stream>>>(actB16, wslot, qkb, vT, 3072, 1024, 1024, 1024, nullptr, nullptr, 0.f);
  gemm_nt<EP_SCALEMASK><<<dim3(32, 32, 1), blk, 0, stream>>>(qkb, qkb + 1024, sbuf, nullptr, N_, 1024, 2048, 2048, nullptr, real_mask, scale);
  softmax_row<false><<<dim3(N_), blk, 0, stream>>>(sbuf, nullptr, aB);
  gemm_nt<EP_F32S><<<dim3(32, 8, 2), blk, 0, stream>>>(aB, vT, gout, goutB, D_, 2048, 4096, 4096, nullptr, nullptr, 0.f);
  add_ln<true><<<dim3(N_), blk, 0, stream>>>(gout, goutB, actB, g3, be3, actA, actB16);
  TCVT(hw1, D_, F_, wslot);
  gemm_nt<EP_BIASGELU_BF16><<<dim3(32, 32, 1), blk, 0, stream>>>(actB16, wslot, tbuf, nullptr, F_, 1024, 1024, 1024, hb1, nullptr, 0.f);
  TCVT(hw2, F_, D_, wslot);
  gemm_nt<EP_BIASZ><<<dim3(32, 8, 2), blk, 0, stream>>>(tbuf, wslot, gout, goutB, D_, 2048, 4096, 4096, hb2, nullptr, 0.f);
  add_ln<true><<<dim3(N_), blk, 0, stream>>>(gout, goutB, actA, g4, be4, out_recon, actB16);

  // ================= head =================
  gather_rows<<<dim3(M_), blk, 0, stream>>>(actB16, mask_nodes, AgB);
  TCVT(head_w, D_, D_, wslot);
  gemm_nt<EP_BIASZ><<<dim3(16, 8, 1), blk, 0, stream>>>(AgB, wslot, gout, nullptr, D_, 1024, 1024, 1024, head_b, nullptr, 0.f);
  gather_recon<<<dim3(M_), 320, 0, stream>>>(gout, gene_idx, out_xrecon);
#undef TCVT
}

// Round 3
// 702.716 us; speedup vs baseline: 1.3918x; 1.0643x over previous
//
#include <hip/hip_runtime.h>
#include <math.h>
#include <stdint.h>

typedef unsigned short u16;
typedef __attribute__((ext_vector_type(8))) short bf16x8;
typedef __attribute__((ext_vector_type(4))) float f32x4;

#define N_ 4096
#define D_ 1024
#define F_ 4096
#define M_ 2048
#define KG 307

__device__ __forceinline__ u16 f2bf(float f) {
  unsigned int u = __float_as_uint(f);
  unsigned int r = u + 0x7fffu + ((u >> 16) & 1u);
  return (u16)(r >> 16);
}

__device__ __forceinline__ void gl_lds16(const u16* g, u16* l) {
  __builtin_amdgcn_global_load_lds(
      (__attribute__((address_space(1))) void*)(void*)g,
      (__attribute__((address_space(3))) void*)(void*)l,
      16, 0, 0);
}

// ============================================================================
// 256x256 8-wave GEMM, BK=32, 4-slot LDS ring (128 KiB), counted vmcnt,
// T2 XOR-swizzle on LDS, T5 setprio, bijective XCD block remap.
// C[M,N] = A[M,K] @ B[N,K]^T  (A,B bf16 row-major k-contiguous)
// ============================================================================
enum { E_QKV = 0, E_SMASK = 1, E_PART = 2, E_GELU = 3 };
#define SMEM_BYTES 131072

template <int EPI>
__global__ __launch_bounds__(512, 2) void gemm256(
    const u16* __restrict__ A, const u16* __restrict__ B,
    void* __restrict__ C, void* __restrict__ C2,
    int gridM, int gridN, int Ndim, int Ksp, int lda, int ldb, long zstr,
    const float* __restrict__ bias, const unsigned char* __restrict__ mask,
    float scale) {
  extern __shared__ __align__(16) char smem[];
  const int tid = threadIdx.x;
  const int lane = tid & 63;
  const int wid = tid >> 6;   // 0..7
  const int wr = wid >> 2;    // 0..1  (M half)
  const int wc = wid & 3;     // 0..3  (N quarter)
  const int lr = lane & 15;
  const int lk = lane >> 4;

  // bijective XCD-chunked remap (m204) + 4-row superblocks for L2 locality
  {
  }
  const int nwg = gridM * gridN;
  const int bid = blockIdx.x;
  const int q8 = nwg >> 3, r8 = nwg & 7;
  const int xcd = bid & 7, ii = bid >> 3;
  int wg = (xcd < r8 ? xcd * (q8 + 1) : r8 * (q8 + 1) + (xcd - r8) * q8) + ii;
  const int rowblk = wg / (gridN << 2);
  const int rem = wg - rowblk * (gridN << 2);
  const int mrem = gridM - (rowblk << 2);
  int mtile, ntile;
  if (mrem >= 4) {
    ntile = rem >> 2;
    mtile = (rowblk << 2) + (rem & 3);
  } else {
    ntile = rem / mrem;
    mtile = (rowblk << 2) + (rem - ntile * mrem);
  }
  const long bm = (long)mtile * 256;
  const long bn = (long)ntile * 256;
  const long koff = (long)blockIdx.y * Ksp;

  // stage tile t into slot s. LDS layout per slot: A[256][32] then B[256][32],
  // 64 B per row, XOR-swizzled: colbyte ^= ((row>>1)&3)<<4 (applied on the
  // GLOBAL source so the linear global_load_lds dest holds swizzled data).
  auto stage = [&](int s, int t) {
    const long k0 = koff + (long)t * 32;
    u16* base = (u16*)(smem + s * 32768);
#pragma unroll
    for (int j = 0; j < 2; ++j) {
      int o = (j << 9) + tid;  // 16B unit index 0..1023
      int row = o >> 2;
      int scb = ((o & 3) << 4) ^ (((row >> 1) & 3) << 4);
      gl_lds16(A + (bm + row) * (long)lda + k0 + (scb >> 1), base + o * 8);
    }
    u16* baseB = base + 8192;
#pragma unroll
    for (int j = 0; j < 2; ++j) {
      int o = (j << 9) + tid;
      int row = o >> 2;
      int scb = ((o & 3) << 4) ^ (((row >> 1) & 3) << 4);
      gl_lds16(B + (bn + row) * (long)ldb + k0 + (scb >> 1), baseB + o * 8);
    }
  };

  stage(0, 0);
  __builtin_amdgcn_sched_barrier(0);
  stage(1, 1);
  __builtin_amdgcn_sched_barrier(0);
  stage(2, 2);
  __builtin_amdgcn_sched_barrier(0);

  f32x4 acc[8][4];
#pragma unroll
  for (int m = 0; m < 8; ++m)
#pragma unroll
    for (int n = 0; n < 4; ++n) acc[m][n] = f32x4{0.f, 0.f, 0.f, 0.f};

  const int NT = Ksp >> 5;
  for (int t = 0; t < NT; ++t) {
    const int s = t & 3;
    const int left = NT - 1 - t;
    // counted vmcnt: tile t's 4 loads are the oldest; keep up to 2 tiles in flight
    if (left >= 2)
      asm volatile("s_waitcnt vmcnt(8)" ::: "memory");
    else if (left == 1)
      asm volatile("s_waitcnt vmcnt(4)" ::: "memory");
    else
      asm volatile("s_waitcnt vmcnt(0)" ::: "memory");
    __builtin_amdgcn_s_barrier();
    __builtin_amdgcn_sched_barrier(0);

    const char* baseA = smem + s * 32768;
    const char* baseB = baseA + 16384;
    bf16x8 av[8], bv[4];
#pragma unroll
    for (int n = 0; n < 4; ++n) {
      int row = (wc << 6) + (n << 4) + lr;
      int cb = (lk << 4) ^ (((row >> 1) & 3) << 4);
      bv[n] = *(const bf16x8*)(baseB + row * 64 + cb);
    }
#pragma unroll
    for (int m = 0; m < 8; ++m) {
      int row = (wr << 7) + (m << 4) + lr;
      int cb = (lk << 4) ^ (((row >> 1) & 3) << 4);
      av[m] = *(const bf16x8*)(baseA + row * 64 + cb);
    }
    // slot (t+3)&3 == (t-1)&3: its last readers finished before this barrier
    if (t + 3 < NT) stage((t + 3) & 3, t + 3);

    __builtin_amdgcn_s_setprio(1);
#pragma unroll
    for (int m = 0; m < 8; ++m)
#pragma unroll
      for (int n = 0; n < 4; ++n)
        acc[m][n] = __builtin_amdgcn_mfma_f32_16x16x32_bf16(av[m], bv[n], acc[m][n], 0, 0, 0);
    __builtin_amdgcn_s_setprio(0);
  }

  const bool z0 = (blockIdx.y == 0);
  float* Cz = (float*)C + (long)blockIdx.y * zstr;
#pragma unroll
  for (int m = 0; m < 8; ++m) {
#pragma unroll
    for (int n = 0; n < 4; ++n) {
#pragma unroll
      for (int j = 0; j < 4; ++j) {
        long row = bm + (wr << 7) + (m << 4) + (lk << 2) + j;
        long col = bn + (wc << 6) + (n << 4) + lr;
        float v = acc[m][n][j];
        if constexpr (EPI == E_QKV) {
          if (col < 2048)
            ((u16*)C)[row * 2048 + col] = f2bf(v);
          else
            ((u16*)C2)[(col - 2048) * (long)N_ + row] = f2bf(v);
        } else if constexpr (EPI == E_SMASK) {
          v *= scale;
          if (mask[row * Ndim + col]) v = -1e9f;
          ((float*)C)[row * Ndim + col] = v;
        } else if constexpr (EPI == E_PART) {
          Cz[row * Ndim + col] = v + ((z0 && bias) ? bias[col] : 0.f);
        } else if constexpr (EPI == E_GELU) {
          float tv = v + bias[col];
          float gl = 0.5f * tv * (1.0f + erff(tv * 0.70710678118654752f));
          ((u16*)C)[row * Ndim + col] = f2bf(gl);
        }
      }
    }
  }
}

// ---------------- 128x128 kernel for the small head GEMM ----------------
__global__ __launch_bounds__(256) void gemm_nt_bias(
    const u16* __restrict__ A, const u16* __restrict__ B, float* __restrict__ C,
    int Ndim, int K, int lda, int ldb, const float* __restrict__ bias) {
  __shared__ u16 As[2][128 * 32];
  __shared__ u16 Bs[2][128 * 32];
  const int tid = threadIdx.x;
  const int lane = tid & 63;
  const int wid = tid >> 6;
  const int wr = wid >> 1;
  const int wc = wid & 1;
  const int lr = lane & 15;
  const int lk = lane >> 4;
  const long bm = (long)blockIdx.x * 128;
  const long bn = (long)blockIdx.y * 128;

  f32x4 acc[4][4];
#pragma unroll
  for (int i = 0; i < 4; ++i)
#pragma unroll
    for (int j = 0; j < 4; ++j) acc[i][j] = f32x4{0.f, 0.f, 0.f, 0.f};

  auto stage = [&](int buf, long k0) {
#pragma unroll
    for (int i = 0; i < 2; ++i) {
      int c = tid + i * 256;
      gl_lds16(A + (bm + (c >> 2)) * (long)lda + k0 + (c & 3) * 8, As[buf] + c * 8);
    }
#pragma unroll
    for (int i = 0; i < 2; ++i) {
      int c = tid + i * 256;
      gl_lds16(B + (bn + (c >> 2)) * (long)ldb + k0 + (c & 3) * 8, Bs[buf] + c * 8);
    }
  };

  stage(0, 0);
  __syncthreads();
  const int nt = K / 32;
  int cur = 0;
  for (int t = 0; t < nt; ++t) {
    if (t + 1 < nt) stage(cur ^ 1, (long)(t + 1) * 32);
    bf16x8 av[4], bv[4];
#pragma unroll
    for (int mr = 0; mr < 4; ++mr)
      av[mr] = *(const bf16x8*)(As[cur] + (wr * 64 + mr * 16 + lr) * 32 + lk * 8);
#pragma unroll
    for (int nr = 0; nr < 4; ++nr)
      bv[nr] = *(const bf16x8*)(Bs[cur] + (wc * 64 + nr * 16 + lr) * 32 + lk * 8);
#pragma unroll
    for (int mr = 0; mr < 4; ++mr)
#pragma unroll
      for (int nr = 0; nr < 4; ++nr)
        acc[mr][nr] = __builtin_amdgcn_mfma_f32_16x16x32_bf16(av[mr], bv[nr], acc[mr][nr], 0, 0, 0);
    __syncthreads();
    cur ^= 1;
  }
#pragma unroll
  for (int mr = 0; mr < 4; ++mr)
#pragma unroll
    for (int nr = 0; nr < 4; ++nr)
#pragma unroll
      for (int j = 0; j < 4; ++j) {
        long row = bm + wr * 64 + mr * 16 + lk * 4 + j;
        long col = bn + wc * 64 + nr * 16 + lr;
        C[row * Ndim + col] = acc[mr][nr][j] + bias[col];
      }
}

// out[c*R + r] = bf16(in[r*C + c])
__global__ __launch_bounds__(256) void tcvt(const float* __restrict__ in,
                                            u16* __restrict__ out, int R, int C) {
  __shared__ float tile[32][33];
  int bx = blockIdx.x * 32;
  int by = blockIdx.y * 32;
  int tx = threadIdx.x & 31;
  int ty = threadIdx.x >> 5;
#pragma unroll
  for (int i = 0; i < 32; i += 8)
    tile[ty + i][tx] = in[(long)(by + ty + i) * C + bx + tx];
  __syncthreads();
#pragma unroll
  for (int i = 0; i < 32; i += 8)
    out[(long)(bx + ty + i) * R + by + tx] = f2bf(tile[tx][ty + i]);
}

__global__ void copy_usex(const float* __restrict__ x, float* __restrict__ xf,
                          u16* __restrict__ xb, long n) {
  long i = (long)blockIdx.x * blockDim.x + threadIdx.x;
  if (i < n) {
    float v = x[i];
    xf[i] = v;
    xb[i] = f2bf(v);
  }
}

__global__ void mask_zero(const float* __restrict__ x, const int* __restrict__ mask_nodes,
                          const int* __restrict__ gene_idx, float* __restrict__ xf,
                          u16* __restrict__ xb, float* __restrict__ x_init) {
  int m = blockIdx.x;
  int k = threadIdx.x;
  if (k >= KG) return;
  int row = mask_nodes[m];
  int col = gene_idx[m * KG + k];
  x_init[m * KG + k] = x[(long)row * D_ + col];
  xf[(long)row * D_ + col] = 0.f;
  xb[(long)row * D_ + col] = 0;
}

// of/ob = LayerNorm(sum_z y[z*ystr] + r) * g + b   (one block per row)
template <int NY>
__global__ __launch_bounds__(256) void add_ln(const float* __restrict__ y, long ystr,
                                              const float* __restrict__ r,
                                              const float* __restrict__ g,
                                              const float* __restrict__ b,
                                              float* __restrict__ of, u16* __restrict__ ob) {
  int row = blockIdx.x;
  const float* yr = y + (long)row * D_;
  const float* rr = r + (long)row * D_;
  float v[4];
  float s = 0.f, ss = 0.f;
#pragma unroll
  for (int i = 0; i < 4; ++i) {
    int idx = threadIdx.x + i * 256;
    float t = rr[idx];
#pragma unroll
    for (int z = 0; z < NY; ++z) t += yr[z * ystr + idx];
    v[i] = t;
    s += t;
    ss += t * t;
  }
#pragma unroll
  for (int o = 32; o > 0; o >>= 1) {
    s += __shfl_down(s, o, 64);
    ss += __shfl_down(ss, o, 64);
  }
  __shared__ float red[8];
  int wid = threadIdx.x >> 6, lane = threadIdx.x & 63;
  if (lane == 0) {
    red[wid] = s;
    red[4 + wid] = ss;
  }
  __syncthreads();
  if (threadIdx.x == 0) {
    red[0] = red[0] + red[1] + red[2] + red[3];
    red[4] = red[4] + red[5] + red[6] + red[7];
  }
  __syncthreads();
  float mu = red[0] * (1.f / D_);
  float var = red[4] * (1.f / D_) - mu * mu;
  float rs = rsqrtf(var + 1e-5f);
#pragma unroll
  for (int i = 0; i < 4; ++i) {
    int idx = threadIdx.x + i * 256;
    float o = (v[i] - mu) * rs * g[idx] + b[idx];
    of[(long)row * D_ + idx] = o;
    ob[(long)row * D_ + idx] = f2bf(o);
  }
}

// row softmax over N_=4096; writes bf16 (and optionally fp32 in-place)
template <bool WF32>
__global__ __launch_bounds__(256) void softmax_row(const float* __restrict__ sin,
                                                   float* __restrict__ a32,
                                                   u16* __restrict__ a16) {
  int row = blockIdx.x;
  const float* sr = sin + (long)row * N_;
  float v[16];
  float mx = -3.0e38f;
#pragma unroll
  for (int i = 0; i < 16; ++i) {
    v[i] = sr[threadIdx.x + i * 256];
    mx = fmaxf(mx, v[i]);
  }
#pragma unroll
  for (int o = 32; o > 0; o >>= 1) mx = fmaxf(mx, __shfl_down(mx, o, 64));
  __shared__ float red[8];
  int wid = threadIdx.x >> 6, lane = threadIdx.x & 63;
  if (lane == 0) red[wid] = mx;
  __syncthreads();
  if (threadIdx.x == 0) red[0] = fmaxf(fmaxf(red[0], red[1]), fmaxf(red[2], red[3]));
  __syncthreads();
  mx = red[0];
  float sum = 0.f;
#pragma unroll
  for (int i = 0; i < 16; ++i) {
    v[i] = __expf(v[i] - mx);
    sum += v[i];
  }
#pragma unroll
  for (int o = 32; o > 0; o >>= 1) sum += __shfl_down(sum, o, 64);
  if (lane == 0) red[4 + wid] = sum;
  __syncthreads();
  if (threadIdx.x == 0) red[4] = red[4] + red[5] + red[6] + red[7];
  __syncthreads();
  float inv = 1.f / red[4];
#pragma unroll
  for (int i = 0; i < 16; ++i) {
    float p = v[i] * inv;
    long off = (long)row * N_ + threadIdx.x + i * 256;
    if constexpr (WF32) a32[off] = p;
    a16[off] = f2bf(p);
  }
}

__global__ void gather_rows(const u16* __restrict__ src, const int* __restrict__ mask_nodes,
                            u16* __restrict__ dst) {
  int m = blockIdx.x;
  int row = mask_nodes[m];
  for (int i = threadIdx.x; i < D_; i += 256)
    dst[(long)m * D_ + i] = src[(long)row * D_ + i];
}

__global__ void gather_recon(const float* __restrict__ h, const int* __restrict__ gene_idx,
                             float* __restrict__ xr) {
  int m = blockIdx.x;
  int k = threadIdx.x;
  if (k >= KG) return;
  xr[m * KG + k] = h[(long)m * D_ + gene_idx[m * KG + k]];
}

extern "C" void kernel_launch(void* const* d_in, const int* in_sizes, int n_in,
                              void* d_out, int out_size, void* d_ws, size_t ws_size,
                              hipStream_t stream) {
  const float* x = (const float*)d_in[0];
  const unsigned char* real_mask = (const unsigned char*)d_in[1];
  const int* mask_nodes = (const int*)d_in[3];
  const int* gene_idx = (const int*)d_in[4];
  const float* wq1 = (const float*)d_in[5];
  const float* wk1 = (const float*)d_in[6];
  const float* wv1 = (const float*)d_in[7];
  const float* g1 = (const float*)d_in[8];
  const float* be1 = (const float*)d_in[9];
  const float* fw1 = (const float*)d_in[10];
  const float* fb1 = (const float*)d_in[11];
  const float* fw2 = (const float*)d_in[12];
  const float* fb2 = (const float*)d_in[13];
  const float* g2 = (const float*)d_in[14];
  const float* be2 = (const float*)d_in[15];
  const float* wq2 = (const float*)d_in[16];
  const float* wk2 = (const float*)d_in[17];
  const float* wv2 = (const float*)d_in[18];
  const float* g3 = (const float*)d_in[19];
  const float* be3 = (const float*)d_in[20];
  const float* hw1 = (const float*)d_in[21];
  const float* hb1 = (const float*)d_in[22];
  const float* hw2 = (const float*)d_in[23];
  const float* hb2 = (const float*)d_in[24];
  const float* g4 = (const float*)d_in[25];
  const float* be4 = (const float*)d_in[26];
  const float* head_w = (const float*)d_in[27];
  const float* head_b = (const float*)d_in[28];

  float* out_xinit = (float*)d_out;
  float* out_xrecon = out_xinit + (long)M_ * KG;
  float* out_enc = out_xrecon + (long)M_ * KG;
  float* out_recon = out_enc + (long)N_ * N_;

  // allow 128 KiB dynamic LDS for all gemm256 instantiations (idempotent)
  hipFuncSetAttribute((const void*)gemm256<E_QKV>, hipFuncAttributeMaxDynamicSharedMemorySize, SMEM_BYTES);
  hipFuncSetAttribute((const void*)gemm256<E_SMASK>, hipFuncAttributeMaxDynamicSharedMemorySize, SMEM_BYTES);
  hipFuncSetAttribute((const void*)gemm256<E_PART>, hipFuncAttributeMaxDynamicSharedMemorySize, SMEM_BYTES);
  hipFuncSetAttribute((const void*)gemm256<E_GELU>, hipFuncAttributeMaxDynamicSharedMemorySize, SMEM_BYTES);

  char* w = (char*)d_ws;
  size_t off = 0;
  auto alloc = [&](size_t bytes) {
    void* p = w + off;
    off += (bytes + 255) & ~(size_t)255;
    return p;
  };
  float* useXf = (float*)alloc((size_t)N_ * D_ * 4);
  u16* useXb = (u16*)alloc((size_t)N_ * D_ * 2);
  u16* wslot = (u16*)alloc((size_t)D_ * F_ * 2);   // weights^T / fused qkv^T
  u16* qkb = (u16*)alloc((size_t)N_ * 2048 * 2);   // q|k  [4096][2048]
  u16* vT = (u16*)alloc((size_t)D_ * N_ * 2);      // v^T  [1024][4096]
  float* sbuf = (float*)alloc((size_t)N_ * N_ * 4);
  u16* aB = (u16*)alloc((size_t)N_ * N_ * 2);
  float* gout4 = (float*)alloc((size_t)4 * N_ * D_ * 4);  // split-K partials
  float* actA = (float*)alloc((size_t)N_ * D_ * 4);
  float* actB = (float*)alloc((size_t)N_ * D_ * 4);
  u16* actB16 = (u16*)alloc((size_t)N_ * D_ * 2);
  u16* tbuf = (u16*)sbuf;  // FFN intermediate (bf16) aliases score buffer
  u16* AgB = qkb;          // gathered masked rows reuse q|k buffer

  const float scale = 1.0f / 32.0f;  // 1/sqrt(D_)
  const long nd = (long)N_ * D_;
  dim3 blk(256), blk5(512);

  copy_usex<<<dim3((unsigned)((nd + 255) / 256)), blk, 0, stream>>>(x, useXf, useXb, nd);
  mask_zero<<<dim3(M_), 320, 0, stream>>>(x, mask_nodes, gene_idx, useXf, useXb, out_xinit);

#define TCVT(src, R, C, dst) tcvt<<<dim3((C) / 32, (R) / 32), blk, 0, stream>>>(src, dst, R, C)
#define G256(EP, GM, GN, Z, A, B, C, C2, ND, KS, LA, LB, ZS, BI, MK, SC)                        \
  gemm256<EP><<<dim3((GM) * (GN), Z), blk5, SMEM_BYTES, stream>>>(A, B, C, C2, GM, GN, ND, KS, \
                                                                  LA, LB, ZS, BI, MK, SC)

  // ================= block 1 =================
  TCVT(wq1, D_, D_, wslot);
  TCVT(wk1, D_, D_, wslot + 1024 * 1024);
  TCVT(wv1, D_, D_, wslot + 2048 * 1024);
  G256(E_QKV, 16, 12, 1, useXb, wslot, qkb, vT, 3072, 1024, 1024, 1024, 0, nullptr, nullptr, 0.f);
  G256(E_SMASK, 16, 16, 1, qkb, qkb + 1024, out_enc, nullptr, 4096, 1024, 2048, 2048, 0, nullptr, real_mask, scale);
  softmax_row<true><<<dim3(N_), blk, 0, stream>>>(out_enc, out_enc, aB);
  G256(E_PART, 16, 4, 4, aB, vT, gout4, nullptr, 1024, 1024, 4096, 4096, nd, nullptr, nullptr, 0.f);
  add_ln<4><<<dim3(N_), blk, 0, stream>>>(gout4, nd, useXf, g1, be1, actA, actB16);
  TCVT(fw1, D_, F_, wslot);
  G256(E_GELU, 16, 16, 1, actB16, wslot, tbuf, nullptr, 4096, 1024, 1024, 1024, 0, fb1, nullptr, 0.f);
  TCVT(fw2, F_, D_, wslot);
  G256(E_PART, 16, 4, 4, tbuf, wslot, gout4, nullptr, 1024, 1024, 4096, 4096, nd, fb2, nullptr, 0.f);
  add_ln<4><<<dim3(N_), blk, 0, stream>>>(gout4, nd, actA, g2, be2, actB, actB16);

  // ================= block 2 =================
  TCVT(wq2, D_, D_, wslot);
  TCVT(wk2, D_, D_, wslot + 1024 * 1024);
  TCVT(wv2, D_, D_, wslot + 2048 * 1024);
  G256(E_QKV, 16, 12, 1, actB16, wslot, qkb, vT, 3072, 1024, 1024, 1024, 0, nullptr, nullptr, 0.f);
  G256(E_SMASK, 16, 16, 1, qkb, qkb + 1024, sbuf, nullptr, 4096, 1024, 2048, 2048, 0, nullptr, real_mask, scale);
  softmax_row<false><<<dim3(N_), blk, 0, stream>>>(sbuf, nullptr, aB);
  G256(E_PART, 16, 4, 4, aB, vT, gout4, nullptr, 1024, 1024, 4096, 4096, nd, nullptr, nullptr, 0.f);
  add_ln<4><<<dim3(N_), blk, 0, stream>>>(gout4, nd, actB, g3, be3, actA, actB16);
  TCVT(hw1, D_, F_, wslot);
  G256(E_GELU, 16, 16, 1, actB16, wslot, tbuf, nullptr, 4096, 1024, 1024, 1024, 0, hb1, nullptr, 0.f);
  TCVT(hw2, F_, D_, wslot);
  G256(E_PART, 16, 4, 4, tbuf, wslot, gout4, nullptr, 1024, 1024, 4096, 4096, nd, hb2, nullptr, 0.f);
  add_ln<4><<<dim3(N_), blk, 0, stream>>>(gout4, nd, actA, g4, be4, out_recon, actB16);

  // ================= head =================
  gather_rows<<<dim3(M_), blk, 0, stream>>>(actB16, mask_nodes, AgB);
  TCVT(head_w, D_, D_, wslot);
  gemm_nt_bias<<<dim3(16, 8), blk, 0, stream>>>(AgB, wslot, gout4, 1024, 1024, 1024, 1024, head_b);
  gather_recon<<<dim3(M_), 320, 0, stream>>>(gout4, gene_idx, out_xrecon);
#undef TCVT
#undef G256
}